// Round 18
// baseline (621.444 us; speedup 1.0000x reference)
//
#include <hip/hip_runtime.h>

// B=8, T=1024, D=1024, H=16, DH=64.
// Column softmax (axis=-2): attn[q,k] = exp(S[q,k])/sum_q' exp(S[q',k]).
// rcpL folded into V (Vts = V * rcpL); C2 (DH^-0.5*log2e) folded into the
// Q-rows of Wqkv at convert time (R11) -> K2/K3 exp2 raw MFMA output.
// K3: S computed TRANSPOSED (A=K, B=Q) so P exits MFMA with q=lane&15,
// k=quad*4+t; Vts stored k-PERMUTED == 16x16x32 per-lane k-set, so
// PV = ONE K=32 MFMA per jd with pc = {exp(st0),exp(st1)} (R10).
// R13-R15: counted-vmcnt pipelining null at 128^2, negative at 256^2;
// the 2-phase 128^2 static-dbuf structure is this session's GEMM floor.
// R16: detect_dtype folded into convert_in (self-probe); K2 setprio. 262.9.
// R17/R18: K2 Q-tiles staged through LDS (fire-and-forget global_load_lds,
// STATIC double-buffer sQ0/sQ1, same sw64 pattern as the K-tile) --
// removes the ~8x ~450cy per-qt Q-gather latency exposure that R11 tried
// (and spilled) to fix with registers; zero VGPR cost. V-tile staged into
// the dead sQ0 slot during the last qt phase. LDS 32.5->48.6KB (3 blk/CU).
// R18 = R17 with the macro-else compile error fixed (do/while(0) hygiene).

typedef __bf16 bf16_t;
typedef __bf16 bf16x8 __attribute__((ext_vector_type(8)));
typedef __bf16 bf16x4 __attribute__((ext_vector_type(4)));
typedef float f32x4 __attribute__((ext_vector_type(4)));
typedef unsigned short u16x8 __attribute__((ext_vector_type(8)));

#define DEV __device__ __forceinline__
#define C2 0.18033688f  // DH^-0.5 * log2(e), folded into Q-rows of Wqkv

DEV void gld_lds16(const bf16_t* g, bf16_t* l) {
  __builtin_amdgcn_global_load_lds(
      (const __attribute__((address_space(1))) unsigned int*)g,
      (__attribute__((address_space(3))) unsigned int*)l, 16, 0, 0);
}

// exp2 via v_exp_f32; upper clamp only (underflow->0 fine); finite always.
DEV float exp2c(float x) { return __builtin_amdgcn_exp2f(fminf(x, 30.f)); }
DEV float sanit(float v) { return (v == v) ? fminf(fmaxf(v, -1e4f), 1e4f) : 0.f; }

// Swizzled chunk (8 bf16 = 16B) offsets in elements. Swizzle baked into the
// staging GLOBAL address so the LDS side stays linear (global_load_lds req).
DEV int sw64(int r, int kc) { return r * 64 + (((kc ^ (r + (r >> 3))) & 7) << 3); }

DEV f32x4 mfma16(bf16x8 a, bf16x8 b, f32x4 c) {
  return __builtin_amdgcn_mfma_f32_16x16x32_bf16(a, b, c, 0, 0, 0);
}

// ---- canonicalize inputs to bf16; per-block dtype probe; Q-rows x C2 -------
// Probe: sample x[0..255] as u16. bf16 data -> all exp fields <= ~134
// (deterministic); fp32 misread -> ~128 mantissa-low words, each ~uniform,
// max exp >= 160 with probability 1 - 0.625^128. All blocks agree.
__global__ void convert_in(const void* __restrict__ x, const void* __restrict__ wq,
                           const void* __restrict__ wp, bf16_t* __restrict__ xb,
                           bf16_t* __restrict__ wqb, bf16_t* __restrict__ wpb,
                           int* __restrict__ flagp) {
  __shared__ int smax;
  if (threadIdx.x == 0) smax = 0;
  __syncthreads();
  {
    int e = (((const unsigned short*)x)[threadIdx.x] >> 7) & 0xFF;
    atomicMax(&smax, e);
  }
  __syncthreads();
  const bool isF32 = smax >= 160;

  int i = blockIdx.x * 256 + threadIdx.x;  // vec8 index, total 1572864
  if (i == 0) *flagp = isF32 ? 1 : 0;      // for K4's output-dtype branch
  const void* src;
  bf16_t* dst;
  int off;
  bool isQ = false;
  if (i < 1048576) { src = x; dst = xb; off = i; }
  else if (i < 1441792) {
    src = wq; dst = wqb; off = i - 1048576;
    isQ = off < 131072;  // rows 0..1023 of Wqkv
  } else { src = wp; dst = wpb; off = i - 1441792; }
  if (isF32) {
    const float s = isQ ? C2 : 1.0f;
    const float4* sp = (const float4*)src;
    float4 a = sp[off * 2], b = sp[off * 2 + 1];
    bf16x8 o;
    o[0] = (bf16_t)(a.x * s); o[1] = (bf16_t)(a.y * s);
    o[2] = (bf16_t)(a.z * s); o[3] = (bf16_t)(a.w * s);
    o[4] = (bf16_t)(b.x * s); o[5] = (bf16_t)(b.y * s);
    o[6] = (bf16_t)(b.z * s); o[7] = (bf16_t)(b.w * s);
    *(bf16x8*)(dst + (size_t)off * 8) = o;
  } else {
    u16x8 v = ((const u16x8*)src)[off];
    if (isQ) {
      bf16x8 bsrc = __builtin_bit_cast(bf16x8, v);
      bf16x8 o;
#pragma unroll
      for (int t = 0; t < 8; ++t) o[t] = (bf16_t)((float)bsrc[t] * C2);
      *(bf16x8*)(dst + (size_t)off * 8) = o;
    } else {
      ((u16x8*)dst)[off] = v;
    }
  }
}

// --------- C[m][n] = sum_k A[m][k]*B[n][k], 128x128 tile, BK=64x2 -----------
// Statically-unrolled LDS double-buffer (R7 body, best-measured e2e):
//   barrier; stage(buf1,k+64); compute(buf0); barrier; stage(buf0,k+128);
//   compute(buf1).  4 distinct __shared__ arrays -> alias analysis resolves
// (R4 lesson). Chunked bijective XCD swizzle (nwg % 8 == 0).
__global__ __launch_bounds__(256, 2)
void gemm_bt(const bf16_t* __restrict__ A, int lda, const bf16_t* __restrict__ B,
             bf16_t* __restrict__ Cb, float* __restrict__ Cf, int ldc,
             int K, const int* __restrict__ f32flag) {
  __shared__ bf16_t sA0[128 * 64];  // 16 KB
  __shared__ bf16_t sB0[128 * 64];
  __shared__ bf16_t sA1[128 * 64];
  __shared__ bf16_t sB1[128 * 64];
  const int tid = threadIdx.x;
  const int wave = tid >> 6, lane = tid & 63;
  const int l = lane & 15, quad = lane >> 4;
  const int nwg = gridDim.x * gridDim.y;
  const int bid = blockIdx.y * gridDim.x + blockIdx.x;
  const int sb = (bid & 7) * (nwg >> 3) + (bid >> 3);
  const int row0 = (sb / gridDim.x) * 128, col0 = (sb % gridDim.x) * 128;
  const int wm = (wave >> 1) * 64, wn = (wave & 1) * 64;
  f32x4 acc[4][4];
#pragma unroll
  for (int i = 0; i < 4; ++i)
#pragma unroll
    for (int j = 0; j < 4; ++j) acc[i][j] = f32x4{0.f, 0.f, 0.f, 0.f};

#define STAGE_G(sa, sb_, kk)                                                  \
  do {                                                                        \
    _Pragma("unroll") for (int t = 0; t < 4; ++t) {                           \
      int n = t * 256 + tid;                                                  \
      int r = n >> 3;                                                         \
      int kc = ((n & 7) ^ (r + (r >> 3))) & 7;                                \
      gld_lds16(A + (size_t)(row0 + r) * lda + (kk) + kc * 8, (sa) + n * 8);  \
      gld_lds16(B + (size_t)(col0 + r) * K + (kk) + kc * 8, (sb_) + n * 8);   \
    }                                                                         \
  } while (0)

#define COMPUTE_G(sa, sb_)                                                    \
  do {                                                                        \
    _Pragma("unroll") for (int ks = 0; ks < 2; ++ks) {                        \
      bf16x8 af[4], bfr[4];                                                   \
      _Pragma("unroll") for (int i = 0; i < 4; ++i) af[i] =                   \
          *(const bf16x8*)&(sa)[sw64(wm + i * 16 + l, ks * 4 + quad)];        \
      _Pragma("unroll") for (int j = 0; j < 4; ++j) bfr[j] =                  \
          *(const bf16x8*)&(sb_)[sw64(wn + j * 16 + l, ks * 4 + quad)];       \
      _Pragma("unroll") for (int i = 0; i < 4; ++i)                           \
          _Pragma("unroll") for (int j = 0; j < 4; ++j) acc[i][j] =           \
              mfma16(af[i], bfr[j], acc[i][j]);                               \
    }                                                                         \
  } while (0)

  STAGE_G(sA0, sB0, 0);
  for (int k0 = 0; k0 < K; k0 += 128) {
    __syncthreads();  // buf0 staged; also orders prev compute(buf1) vs refill
    if (k0 + 64 < K) STAGE_G(sA1, sB1, k0 + 64);
    COMPUTE_G(sA0, sB0);
    __syncthreads();  // buf1 staged; orders compute(buf0) vs buf0 refill
    if (k0 + 128 < K) STAGE_G(sA0, sB0, k0 + 128);
    COMPUTE_G(sA1, sB1);
  }
#undef STAGE_G
#undef COMPUTE_G

  const bool of32 = (f32flag != nullptr) && (*f32flag != 0);
#pragma unroll
  for (int i = 0; i < 4; ++i) {
    int rr = row0 + wm + i * 16 + quad * 4;
#pragma unroll
    for (int j = 0; j < 4; ++j) {
      int cc = col0 + wn + j * 16 + l;
#pragma unroll
      for (int t = 0; t < 4; ++t) {
        float v = sanit(acc[i][j][t]);
        size_t idx = (size_t)(rr + t) * ldc + cc;
        if (of32) Cf[idx] = v; else Cb[idx] = (bf16_t)v;
      }
    }
  }
}

// ------------- K2: column sumexp L[k]; write Vts = V * (1/L) -----------------
// R18: Q-tiles staged through LDS (static dbuf sQ0/sQ1, global_load_lds,
// same sw64 pattern as the K-tile) -- removes the per-qt Q-gather latency
// with zero VGPR cost. V-tile staged into the dead sQ0 slot during the
// last qt phase; the Vts-write epilogue reads it there. T5 setprio kept.
// Vts write is k-PERMUTED within each 32-chunk (see K3 header comment).
__global__ __launch_bounds__(256, 3)
void attn_stats(const bf16_t* __restrict__ qkv, bf16_t* __restrict__ Vts) {
  __shared__ bf16_t sKp[128 * 64];  // K-tile (16 KB)
  __shared__ bf16_t sQ0[128 * 64];  // Q-tile even buf; V-tile in epilogue
  __shared__ bf16_t sQ1[128 * 64];  // Q-tile odd buf
  __shared__ float sL[128];
  const int bh = blockIdx.x, kt = blockIdx.y;
  const int b = bh >> 4, h = bh & 15;
  const int tid = threadIdx.x, wave = tid >> 6, lane = tid & 63;
  const int l = lane & 15, quad = lane >> 4;
  const size_t rowK = (size_t)b * 1024 + kt * 128;

#define STAGEQ(dst, qt)                                                       \
  do {                                                                        \
    _Pragma("unroll") for (int t = 0; t < 4; ++t) {                           \
      int base = wave * 256 + t * 64;                                         \
      int n = base + lane;                                                    \
      int r = n >> 3;                                                         \
      int kc = ((n & 7) ^ (r + (r >> 3))) & 7;                                \
      gld_lds16(qkv + ((size_t)b * 1024 + (qt) * 128 + r) * 3072 + h * 64 +   \
                    kc * 8,                                                   \
                (dst) + base * 8);                                            \
    }                                                                         \
  } while (0)

#define STAGEV(dst)                                                           \
  do {                                                                        \
    _Pragma("unroll") for (int t = 0; t < 4; ++t) {                           \
      int base = wave * 256 + t * 64;                                         \
      int n = base + lane;                                                    \
      int r = n >> 3;                                                         \
      int kc = ((n & 7) ^ (r + (r >> 3))) & 7;                                \
      gld_lds16(qkv + (rowK + r) * 3072 + 2048 + h * 64 + kc * 8,             \
                (dst) + base * 8);                                            \
    }                                                                         \
  } while (0)

#define QT_BODY(sQb)                                                          \
  do {                                                                        \
    bf16x8 aq[2][2];                                                          \
    _Pragma("unroll") for (int i2 = 0; i2 < 2; ++i2)                          \
        _Pragma("unroll") for (int ks = 0; ks < 2; ++ks) aq[i2][ks] =         \
            *(const bf16x8*)&(sQb)[sw64(wave * 32 + i2 * 16 + l,              \
                                        ks * 4 + quad)];                      \
    _Pragma("unroll") for (int j = 0; j < 8; ++j) {                           \
      f32x4 s0 = {0.f, 0.f, 0.f, 0.f}, s1 = {0.f, 0.f, 0.f, 0.f};            \
      __builtin_amdgcn_s_setprio(1);                                          \
      _Pragma("unroll") for (int ks = 0; ks < 2; ++ks) {                      \
        bf16x8 bk = *(const bf16x8*)&sKp[sw64(j * 16 + l, ks * 4 + quad)];    \
        s0 = mfma16(aq[0][ks], bk, s0);                                       \
        s1 = mfma16(aq[1][ks], bk, s1);                                       \
      }                                                                       \
      __builtin_amdgcn_s_setprio(0);                                          \
      _Pragma("unroll") for (int t = 0; t < 4; ++t)                           \
          accj[j] += exp2c(s0[t]) + exp2c(s1[t]);                             \
    }                                                                         \
  } while (0)

  // prologue: stage K-tile + Q-tile(0)
#pragma unroll
  for (int t = 0; t < 4; ++t) {
    int base = wave * 256 + t * 64;
    int n = base + lane;
    int r = n >> 3;
    int kc = ((n & 7) ^ (r + (r >> 3))) & 7;
    gld_lds16(qkv + (rowK + r) * 3072 + 1024 + h * 64 + kc * 8, sKp + base * 8);
    gld_lds16(qkv + ((size_t)b * 1024 + r) * 3072 + h * 64 + kc * 8,
              sQ0 + base * 8);
  }
  if (tid < 128) sL[tid] = 0.f;
  __syncthreads();  // K + Q0 staged (implicit vmcnt drain)

  float accj[8];
#pragma unroll
  for (int j = 0; j < 8; ++j) accj[j] = 0.f;

#pragma unroll
  for (int qt = 0; qt < 8; qt += 2) {
    STAGEQ(sQ1, qt + 1);   // flies under tile-qt compute
    QT_BODY(sQ0);
    __syncthreads();       // drains sQ1 stage; orders sQ0 readers vs refill
    if (qt + 2 < 8) {
      STAGEQ(sQ0, qt + 2);
    } else {
      STAGEV(sQ0);
    }
    QT_BODY(sQ1);
    __syncthreads();       // drains sQ0/V stage; orders sQ1 readers vs refill
  }
#undef STAGEQ
#undef STAGEV
#undef QT_BODY

#pragma unroll
  for (int j = 0; j < 8; ++j) {
    float v = accj[j];
    v += __shfl_xor(v, 16);
    v += __shfl_xor(v, 32);
    if (lane < 16) atomicAdd(&sL[j * 16 + l], v);
  }
  __syncthreads();
  if (tid < 128) sL[tid] = 1.0f / fmaxf(sL[tid], 1e-20f);
  __syncthreads();

  // write V transposed, scaled, k-permuted (V-tile lives in sQ0):
  // storage pos (chunk base | i) holds logical k = base | kk*16 | quad*4 | t
  // where kk=(i>>2), quad=(k0>>3)&3, t=i&3.
#pragma unroll
  for (int t = 0; t < 4; ++t) {
    int u = t * 256 + tid;
    int d = u >> 4, k0 = (u & 15) * 8;
    bf16x8 pk;
#pragma unroll
    for (int i = 0; i < 8; ++i) {
      int kl = (k0 & ~31) | ((i >> 2) << 4) | (((k0 >> 3) & 3) << 2) | (i & 3);
      float v = (float)sQ0[sw64(kl, d >> 3) + (d & 7)];
      pk[i] = (bf16_t)(v * sL[kl]);
    }
    *(bf16x8*)&Vts[((size_t)bh * 64 + d) * 1024 + kt * 128 + k0] = pk;
  }
}

// ------------- K3: O[q][d] = sum_k exp2(Ss[q,k]) * Vts[d][k] -----------------
// R12 body (frozen). PV = single K=32 MFMA per jd; P stays in registers.
// K/Vts tiles staged in LDS (global_load_lds, dbuf, prefetched 1 kt ahead);
// Vts LDS [64 d][128 k] with chunk ^= d&7 swizzle (2-way-free reads).
// 512 threads, LDS 64KB -> 2 blocks/CU -> 16 waves/CU. T5 setprio.
__global__ __launch_bounds__(512, 4)
void attn_out_k(const bf16_t* __restrict__ qkv, const bf16_t* __restrict__ Vts,
                bf16_t* __restrict__ attn) {
  __shared__ bf16_t sK[2][128 * 64];  // 16 KB x2: [k][dh], sw64-swizzled
  __shared__ bf16_t sV[2][64 * 128];  // 16 KB x2: [d][k], chunk^= d&7
  const int bh = blockIdx.x, qt = blockIdx.y;  // qt in [0,4): 256 q-rows/block
  const int b = bh >> 4, h = bh & 15;
  const int tid = threadIdx.x, wave = tid >> 6, lane = tid & 63;
  const int l = lane & 15, quad = lane >> 4;
  const bf16_t* qbase = qkv + (size_t)b * 3145728 + h * 64;  // row stride 3072
  const bf16_t* vbase = Vts + (size_t)bh * 65536;            // row stride 1024

  // Q B-fragments (loop-invariant): B[n=q][dk = ks*32 + quad*8 + j]
  bf16x8 bq[2][2];
#pragma unroll
  for (int i = 0; i < 2; ++i)
#pragma unroll
    for (int ks = 0; ks < 2; ++ks)
      bq[i][ks] = *(const bf16x8*)&qbase[(size_t)(qt * 256 + wave * 32 + i * 16 + l) *
                                             3072 + ks * 32 + quad * 8];
  f32x4 o[2][4];  // o[i=qtile][jd=dtile] : D[m=d][n=q]
#pragma unroll
  for (int i = 0; i < 2; ++i)
#pragma unroll
    for (int jd = 0; jd < 4; ++jd) o[i][jd] = f32x4{0.f, 0.f, 0.f, 0.f};

  // stage kt=0 -> buf 0 (K: 1024 chunks; V: 1024 chunks; 2 each per thread)
#pragma unroll
  for (int t = 0; t < 2; ++t) {
    int n = t * 512 + tid;
    int r = n >> 3;
    int kc = ((n & 7) ^ (r + (r >> 3))) & 7;
    gld_lds16(qkv + ((size_t)b * 1024 + r) * 3072 + 1024 + h * 64 + kc * 8,
              sK[0] + n * 8);
    int d = n >> 4, s = n & 15;
    int c = s ^ (d & 7);
    gld_lds16(vbase + (size_t)d * 1024 + c * 8, sV[0] + n * 8);
  }

  for (int kt = 0; kt < 8; ++kt) {
    const int buf = kt & 1;
    __syncthreads();  // drains stage(kt); orders buf^1 refill vs prev reads
    if (kt < 7) {
#pragma unroll
      for (int t = 0; t < 2; ++t) {
        int n = t * 512 + tid;
        int r = n >> 3;
        int kc = ((n & 7) ^ (r + (r >> 3))) & 7;
        gld_lds16(qkv + ((size_t)b * 1024 + (kt + 1) * 128 + r) * 3072 + 1024 +
                      h * 64 + kc * 8,
                  sK[buf ^ 1] + n * 8);
        int d = n >> 4, s = n & 15;
        int c = s ^ (d & 7);
        gld_lds16(vbase + (size_t)d * 1024 + (kt + 1) * 128 + c * 8,
                  sV[buf ^ 1] + n * 8);
      }
    }
    const bf16_t* sKb = sK[buf];
    const bf16_t* sVb = sV[buf];

#pragma unroll
    for (int ch = 0; ch < 4; ++ch) {  // 32-k chunks
      // K A-frags: A[m=k=ch*32+kk*16+l][dk] -- i-invariant, hoisted
      bf16x8 ak[2][2];
#pragma unroll
      for (int kk = 0; kk < 2; ++kk)
#pragma unroll
        for (int ks = 0; ks < 2; ++ks)
          ak[kk][ks] = *(const bf16x8*)&sKb[sw64(ch * 32 + kk * 16 + l,
                                                 ks * 4 + quad)];
      // Vts A-frags from LDS: row d=jd*16+l, logical chunk ch*4+quad,
      // storage chunk = logical ^ (l&7)  (d&7 == l&7 since jd*16%8==0)
      bf16x8 va[4];
#pragma unroll
      for (int jd = 0; jd < 4; ++jd)
        va[jd] = *(const bf16x8*)&sVb[(jd * 16 + l) * 128 +
                                      (((ch * 4 + quad) ^ (l & 7)) << 3)];
#pragma unroll
      for (int i = 0; i < 2; ++i) {  // q-tiles
        __builtin_amdgcn_s_setprio(1);
        // Ss^T tiles (kk=0,1); Q pre-scaled by C2
        f32x4 st0 = {0.f, 0.f, 0.f, 0.f}, st1 = {0.f, 0.f, 0.f, 0.f};
        st0 = mfma16(ak[0][0], bq[i][0], st0);
        st0 = mfma16(ak[0][1], bq[i][1], st0);
        st1 = mfma16(ak[1][0], bq[i][0], st1);
        st1 = mfma16(ak[1][1], bq[i][1], st1);
        // pc = exp2(Ss^T) concatenated: slot quad*8+j <-> Vts storage slot
        bf16x8 pc;
#pragma unroll
        for (int t = 0; t < 4; ++t) {
          pc[t] = (bf16_t)exp2c(st0[t]);
          pc[4 + t] = (bf16_t)exp2c(st1[t]);
        }
#pragma unroll
        for (int jd = 0; jd < 4; ++jd)
          o[i][jd] = mfma16(va[jd], pc, o[i][jd]);
        __builtin_amdgcn_s_setprio(0);
      }
    }
  }
  // epilogue: q = qt*256+wave*32+i*16+l, d = jd*16+quad*4+{0..3} -> 8B stores
#pragma unroll
  for (int i = 0; i < 2; ++i) {
    size_t row = (size_t)b * 1024 + qt * 256 + wave * 32 + i * 16 + l;
#pragma unroll
    for (int jd = 0; jd < 4; ++jd) {
      bf16x4 pk;
#pragma unroll
      for (int t = 0; t < 4; ++t) pk[t] = (bf16_t)sanit(o[i][jd][t]);
      *(bf16x4*)&attn[row * 3072 + h * 64 + jd * 16 + quad * 4] = pk;
    }
  }
}

extern "C" void kernel_launch(void* const* d_in, const int* in_sizes, int n_in,
                              void* d_out, int out_size, void* d_ws, size_t ws_size,
                              hipStream_t stream) {
  (void)in_sizes; (void)n_in; (void)out_size; (void)ws_size;
  char* w = (char*)d_ws;
  bf16_t* qkv = (bf16_t*)w;                 // [0, 50331648)
  bf16_t* xb = (bf16_t*)(w + 50331648);     // [50331648, 67108864) -> Vts after K1
  bf16_t* Vts = xb;
  bf16_t* Wqkvb = (bf16_t*)(w + 67108864);  // [67108864, 73400320)
  bf16_t* Wprojb = (bf16_t*)(w + 73400320); // [73400320, 75497472)
  int* flag = (int*)(w + 75497472);
  bf16_t* attn = qkv + 2048;                // V-columns of qkv, stride 3072

  // convert: self-probing dtype (writes flag for K4); Q-rows scaled by C2
  convert_in<<<6144, 256, 0, stream>>>(d_in[0], d_in[1], d_in[2],
                                       xb, Wqkvb, Wprojb, flag);

  // K1: qkv = x @ Wqkv^T  (8192 x 3072, K=1024), grid 24*64=1536 (%8==0)
  gemm_bt<<<dim3(24, 64), 256, 0, stream>>>(xb, 1024, Wqkvb, qkv, nullptr, 3072,
                                            1024, nullptr);
  // K2: column-softmax denominators folded into Vts (permuted layout)
  attn_stats<<<dim3(128, 8), 256, 0, stream>>>(qkv, Vts);
  // K3: attention output -> qkv V-columns (512 thr, 256 q-rows/block)
  attn_out_k<<<dim3(128, 4), 512, 0, stream>>>(qkv, Vts, attn);
  // K4: out = attn @ Wproj^T  (8192 x 1024, K=1024), grid 8*64=512 (%8==0)
  gemm_bt<<<dim3(8, 64), 256, 0, stream>>>(attn, 3072, Wprojb, (bf16_t*)d_out,
                                           (float*)d_out, 1024, 1024, flag);
}

// Round 19
// 258.899 us; speedup vs baseline: 2.4003x; 2.4003x over previous
//
#include <hip/hip_runtime.h>

// B=8, T=1024, D=1024, H=16, DH=64.
// Column softmax (axis=-2): attn[q,k] = exp(S[q,k])/sum_q' exp(S[q',k]).
// rcpL folded into V (Vts = V * rcpL); C2 (DH^-0.5*log2e) folded into the
// Q-rows of Wqkv at convert time (R11) -> K2/K3 exp2 raw MFMA output.
// K3: S computed TRANSPOSED (A=K, B=Q) so P exits MFMA with q=lane&15,
// k=quad*4+t; Vts stored k-PERMUTED (chunk pos quad*8+j holds logical
// k = j<4 ? quad*4+j : 16+quad*4+(j-4)) == the 16x16x32 per-lane k-set,
// so PV = ONE K=32 MFMA per jd with pc = {exp(st0),exp(st1)} (R10).
// Session ledger: 2-phase 128^2 static-dbuf is the GEMM floor (R13 null,
// R15 negative at 256^2; R6/R8 identical binaries spread 64->78us = noise).
// K2 inner-loop restructures trigger spill-class codegen BOTH times tried
// (R11: reg-prefetch, WRITE 372MB; R18: LDS-staged Q, WRITE 610MB) -- the
// harness's VGPR_Count does not surface scratch. K2 is frozen at the R12
// body + isolated setprio (R16-verified).
// R19 = byte-identical restore of the R16 module (best measured: 262.9us).

typedef __bf16 bf16_t;
typedef __bf16 bf16x8 __attribute__((ext_vector_type(8)));
typedef __bf16 bf16x4 __attribute__((ext_vector_type(4)));
typedef float f32x4 __attribute__((ext_vector_type(4)));
typedef unsigned short u16x8 __attribute__((ext_vector_type(8)));

#define DEV __device__ __forceinline__
#define C2 0.18033688f  // DH^-0.5 * log2(e), folded into Q-rows of Wqkv

DEV void gld_lds16(const bf16_t* g, bf16_t* l) {
  __builtin_amdgcn_global_load_lds(
      (const __attribute__((address_space(1))) unsigned int*)g,
      (__attribute__((address_space(3))) unsigned int*)l, 16, 0, 0);
}

// exp2 via v_exp_f32; upper clamp only (underflow->0 fine); finite always.
DEV float exp2c(float x) { return __builtin_amdgcn_exp2f(fminf(x, 30.f)); }
DEV float sanit(float v) { return (v == v) ? fminf(fmaxf(v, -1e4f), 1e4f) : 0.f; }

// Swizzled chunk (8 bf16 = 16B) offsets in elements. Swizzle baked into the
// staging GLOBAL address so the LDS side stays linear (global_load_lds req).
DEV int sw64(int r, int kc) { return r * 64 + (((kc ^ (r + (r >> 3))) & 7) << 3); }

DEV f32x4 mfma16(bf16x8 a, bf16x8 b, f32x4 c) {
  return __builtin_amdgcn_mfma_f32_16x16x32_bf16(a, b, c, 0, 0, 0);
}

// ---- canonicalize inputs to bf16; per-block dtype probe; Q-rows x C2 -------
// Probe: sample x[0..255] as u16. bf16 data -> all exp fields <= ~134
// (deterministic); fp32 misread -> ~128 mantissa-low words, each ~uniform,
// max exp >= 160 with probability 1 - 0.625^128. All blocks agree.
__global__ void convert_in(const void* __restrict__ x, const void* __restrict__ wq,
                           const void* __restrict__ wp, bf16_t* __restrict__ xb,
                           bf16_t* __restrict__ wqb, bf16_t* __restrict__ wpb,
                           int* __restrict__ flagp) {
  __shared__ int smax;
  if (threadIdx.x == 0) smax = 0;
  __syncthreads();
  {
    int e = (((const unsigned short*)x)[threadIdx.x] >> 7) & 0xFF;
    atomicMax(&smax, e);
  }
  __syncthreads();
  const bool isF32 = smax >= 160;

  int i = blockIdx.x * 256 + threadIdx.x;  // vec8 index, total 1572864
  if (i == 0) *flagp = isF32 ? 1 : 0;      // for K4's output-dtype branch
  const void* src;
  bf16_t* dst;
  int off;
  bool isQ = false;
  if (i < 1048576) { src = x; dst = xb; off = i; }
  else if (i < 1441792) {
    src = wq; dst = wqb; off = i - 1048576;
    isQ = off < 131072;  // rows 0..1023 of Wqkv
  } else { src = wp; dst = wpb; off = i - 1441792; }
  if (isF32) {
    const float s = isQ ? C2 : 1.0f;
    const float4* sp = (const float4*)src;
    float4 a = sp[off * 2], b = sp[off * 2 + 1];
    bf16x8 o;
    o[0] = (bf16_t)(a.x * s); o[1] = (bf16_t)(a.y * s);
    o[2] = (bf16_t)(a.z * s); o[3] = (bf16_t)(a.w * s);
    o[4] = (bf16_t)(b.x * s); o[5] = (bf16_t)(b.y * s);
    o[6] = (bf16_t)(b.z * s); o[7] = (bf16_t)(b.w * s);
    *(bf16x8*)(dst + (size_t)off * 8) = o;
  } else {
    u16x8 v = ((const u16x8*)src)[off];
    if (isQ) {
      bf16x8 bsrc = __builtin_bit_cast(bf16x8, v);
      bf16x8 o;
#pragma unroll
      for (int t = 0; t < 8; ++t) o[t] = (bf16_t)((float)bsrc[t] * C2);
      *(bf16x8*)(dst + (size_t)off * 8) = o;
    } else {
      ((u16x8*)dst)[off] = v;
    }
  }
}

// --------- C[m][n] = sum_k A[m][k]*B[n][k], 128x128 tile, BK=64x2 -----------
// Statically-unrolled LDS double-buffer (R7 body, best-measured e2e):
//   barrier; stage(buf1,k+64); compute(buf0); barrier; stage(buf0,k+128);
//   compute(buf1).  4 distinct __shared__ arrays -> alias analysis resolves
// (R4 lesson). Chunked bijective XCD swizzle (nwg % 8 == 0).
__global__ __launch_bounds__(256, 2)
void gemm_bt(const bf16_t* __restrict__ A, int lda, const bf16_t* __restrict__ B,
             bf16_t* __restrict__ Cb, float* __restrict__ Cf, int ldc,
             int K, const int* __restrict__ f32flag) {
  __shared__ bf16_t sA0[128 * 64];  // 16 KB
  __shared__ bf16_t sB0[128 * 64];
  __shared__ bf16_t sA1[128 * 64];
  __shared__ bf16_t sB1[128 * 64];
  const int tid = threadIdx.x;
  const int wave = tid >> 6, lane = tid & 63;
  const int l = lane & 15, quad = lane >> 4;
  const int nwg = gridDim.x * gridDim.y;
  const int bid = blockIdx.y * gridDim.x + blockIdx.x;
  const int sb = (bid & 7) * (nwg >> 3) + (bid >> 3);
  const int row0 = (sb / gridDim.x) * 128, col0 = (sb % gridDim.x) * 128;
  const int wm = (wave >> 1) * 64, wn = (wave & 1) * 64;
  f32x4 acc[4][4];
#pragma unroll
  for (int i = 0; i < 4; ++i)
#pragma unroll
    for (int j = 0; j < 4; ++j) acc[i][j] = f32x4{0.f, 0.f, 0.f, 0.f};

#define STAGE_G(sa, sb_, kk)                                                  \
  do {                                                                        \
    _Pragma("unroll") for (int t = 0; t < 4; ++t) {                           \
      int n = t * 256 + tid;                                                  \
      int r = n >> 3;                                                         \
      int kc = ((n & 7) ^ (r + (r >> 3))) & 7;                                \
      gld_lds16(A + (size_t)(row0 + r) * lda + (kk) + kc * 8, (sa) + n * 8);  \
      gld_lds16(B + (size_t)(col0 + r) * K + (kk) + kc * 8, (sb_) + n * 8);   \
    }                                                                         \
  } while (0)

#define COMPUTE_G(sa, sb_)                                                    \
  do {                                                                        \
    _Pragma("unroll") for (int ks = 0; ks < 2; ++ks) {                        \
      bf16x8 af[4], bfr[4];                                                   \
      _Pragma("unroll") for (int i = 0; i < 4; ++i) af[i] =                   \
          *(const bf16x8*)&(sa)[sw64(wm + i * 16 + l, ks * 4 + quad)];        \
      _Pragma("unroll") for (int j = 0; j < 4; ++j) bfr[j] =                  \
          *(const bf16x8*)&(sb_)[sw64(wn + j * 16 + l, ks * 4 + quad)];       \
      _Pragma("unroll") for (int i = 0; i < 4; ++i)                           \
          _Pragma("unroll") for (int j = 0; j < 4; ++j) acc[i][j] =           \
              mfma16(af[i], bfr[j], acc[i][j]);                               \
    }                                                                         \
  } while (0)

  STAGE_G(sA0, sB0, 0);
  for (int k0 = 0; k0 < K; k0 += 128) {
    __syncthreads();  // buf0 staged; also orders prev compute(buf1) vs refill
    if (k0 + 64 < K) STAGE_G(sA1, sB1, k0 + 64);
    COMPUTE_G(sA0, sB0);
    __syncthreads();  // buf1 staged; orders compute(buf0) vs buf0 refill
    if (k0 + 128 < K) STAGE_G(sA0, sB0, k0 + 128);
    COMPUTE_G(sA1, sB1);
  }
#undef STAGE_G
#undef COMPUTE_G

  const bool of32 = (f32flag != nullptr) && (*f32flag != 0);
#pragma unroll
  for (int i = 0; i < 4; ++i) {
    int rr = row0 + wm + i * 16 + quad * 4;
#pragma unroll
    for (int j = 0; j < 4; ++j) {
      int cc = col0 + wn + j * 16 + l;
#pragma unroll
      for (int t = 0; t < 4; ++t) {
        float v = sanit(acc[i][j][t]);
        size_t idx = (size_t)(rr + t) * ldc + cc;
        if (of32) Cf[idx] = v; else Cb[idx] = (bf16_t)v;
      }
    }
  }
}

// ------------- K2: column sumexp L[k]; write Vts = V * (1/L) -----------------
// R12 body + isolated T5 setprio (R16-verified). Q pre-scaled by C2 ->
// exp2 on raw MFMA output. Per-lane accj[] defers reduction: 8 atomics/
// wave. Vts write is k-PERMUTED within each 32-chunk (K3 header comment).
__global__ __launch_bounds__(256, 4)
void attn_stats(const bf16_t* __restrict__ qkv, bf16_t* __restrict__ Vts) {
  __shared__ bf16_t sK[128 * 64];
  __shared__ bf16_t sV[128 * 64];
  __shared__ float sL[128];
  const int bh = blockIdx.x, kt = blockIdx.y;
  const int b = bh >> 4, h = bh & 15;
  const int tid = threadIdx.x, wave = tid >> 6, lane = tid & 63;
  const int l = lane & 15, quad = lane >> 4;
  const size_t rowK = (size_t)b * 1024 + kt * 128;

  // stage V-tile and K-tile (swizzled)
#pragma unroll
  for (int t = 0; t < 4; ++t) {
    int base = wave * 256 + t * 64;
    int n = base + lane;
    int r = n >> 3;
    int kc = ((n & 7) ^ (r + (r >> 3))) & 7;
    gld_lds16(qkv + (rowK + r) * 3072 + 2048 + h * 64 + kc * 8, sV + base * 8);
    gld_lds16(qkv + (rowK + r) * 3072 + 1024 + h * 64 + kc * 8, sK + base * 8);
  }
  if (tid < 128) sL[tid] = 0.f;
  __syncthreads();

  float accj[8];
#pragma unroll
  for (int j = 0; j < 8; ++j) accj[j] = 0.f;

  for (int qt = 0; qt < 8; ++qt) {
    bf16x8 aq[2][2];
#pragma unroll
    for (int i = 0; i < 2; ++i)
#pragma unroll
      for (int ks = 0; ks < 2; ++ks)
        aq[i][ks] = *(const bf16x8*)&qkv[((size_t)b * 1024 + qt * 128 + wave * 32 +
                                          i * 16 + l) * 3072 + h * 64 +
                                         (ks * 4 + quad) * 8];
#pragma unroll
    for (int j = 0; j < 8; ++j) {
      f32x4 s0 = {0.f, 0.f, 0.f, 0.f}, s1 = {0.f, 0.f, 0.f, 0.f};
      __builtin_amdgcn_s_setprio(1);
#pragma unroll
      for (int ks = 0; ks < 2; ++ks) {
        bf16x8 bk = *(const bf16x8*)&sK[sw64(j * 16 + l, ks * 4 + quad)];
        s0 = mfma16(aq[0][ks], bk, s0);
        s1 = mfma16(aq[1][ks], bk, s1);
      }
      __builtin_amdgcn_s_setprio(0);
#pragma unroll
      for (int t = 0; t < 4; ++t)
        accj[j] += exp2c(s0[t]) + exp2c(s1[t]);
    }
  }
#pragma unroll
  for (int j = 0; j < 8; ++j) {
    float v = accj[j];
    v += __shfl_xor(v, 16);
    v += __shfl_xor(v, 32);
    if (lane < 16) atomicAdd(&sL[j * 16 + l], v);
  }
  __syncthreads();
  if (tid < 128) sL[tid] = 1.0f / fmaxf(sL[tid], 1e-20f);
  __syncthreads();

  // write V transposed, scaled, k-permuted:
  // storage pos (chunk base | i) holds logical k = base | kk*16 | quad*4 | t
  // where kk=(i>>2), quad=(k0>>3)&3, t=i&3.
#pragma unroll
  for (int t = 0; t < 4; ++t) {
    int u = t * 256 + tid;
    int d = u >> 4, k0 = (u & 15) * 8;
    bf16x8 pk;
#pragma unroll
    for (int i = 0; i < 8; ++i) {
      int kl = (k0 & ~31) | ((i >> 2) << 4) | (((k0 >> 3) & 3) << 2) | (i & 3);
      float v = (float)sV[sw64(kl, d >> 3) + (d & 7)];
      pk[i] = (bf16_t)(v * sL[kl]);
    }
    *(bf16x8*)&Vts[((size_t)bh * 64 + d) * 1024 + kt * 128 + k0] = pk;
  }
}

// ------------- K3: O[q][d] = sum_k exp2(Ss[q,k]) * Vts[d][k] -----------------
// R12 body (frozen). PV = single K=32 MFMA per jd; P stays in registers.
// K/Vts tiles staged in LDS (global_load_lds, dbuf, prefetched 1 kt ahead);
// Vts LDS [64 d][128 k] with chunk ^= d&7 swizzle (2-way-free reads).
// 512 threads, LDS 64KB -> 2 blocks/CU -> 16 waves/CU. T5 setprio.
__global__ __launch_bounds__(512, 4)
void attn_out_k(const bf16_t* __restrict__ qkv, const bf16_t* __restrict__ Vts,
                bf16_t* __restrict__ attn) {
  __shared__ bf16_t sK[2][128 * 64];  // 16 KB x2: [k][dh], sw64-swizzled
  __shared__ bf16_t sV[2][64 * 128];  // 16 KB x2: [d][k], chunk^= d&7
  const int bh = blockIdx.x, qt = blockIdx.y;  // qt in [0,4): 256 q-rows/block
  const int b = bh >> 4, h = bh & 15;
  const int tid = threadIdx.x, wave = tid >> 6, lane = tid & 63;
  const int l = lane & 15, quad = lane >> 4;
  const bf16_t* qbase = qkv + (size_t)b * 3145728 + h * 64;  // row stride 3072
  const bf16_t* vbase = Vts + (size_t)bh * 65536;            // row stride 1024

  // Q B-fragments (loop-invariant): B[n=q][dk = ks*32 + quad*8 + j]
  bf16x8 bq[2][2];
#pragma unroll
  for (int i = 0; i < 2; ++i)
#pragma unroll
    for (int ks = 0; ks < 2; ++ks)
      bq[i][ks] = *(const bf16x8*)&qbase[(size_t)(qt * 256 + wave * 32 + i * 16 + l) *
                                             3072 + ks * 32 + quad * 8];
  f32x4 o[2][4];  // o[i=qtile][jd=dtile] : D[m=d][n=q]
#pragma unroll
  for (int i = 0; i < 2; ++i)
#pragma unroll
    for (int jd = 0; jd < 4; ++jd) o[i][jd] = f32x4{0.f, 0.f, 0.f, 0.f};

  // stage kt=0 -> buf 0 (K: 1024 chunks; V: 1024 chunks; 2 each per thread)
#pragma unroll
  for (int t = 0; t < 2; ++t) {
    int n = t * 512 + tid;
    int r = n >> 3;
    int kc = ((n & 7) ^ (r + (r >> 3))) & 7;
    gld_lds16(qkv + ((size_t)b * 1024 + r) * 3072 + 1024 + h * 64 + kc * 8,
              sK[0] + n * 8);
    int d = n >> 4, s = n & 15;
    int c = s ^ (d & 7);
    gld_lds16(vbase + (size_t)d * 1024 + c * 8, sV[0] + n * 8);
  }

  for (int kt = 0; kt < 8; ++kt) {
    const int buf = kt & 1;
    __syncthreads();  // drains stage(kt); orders buf^1 refill vs prev reads
    if (kt < 7) {
#pragma unroll
      for (int t = 0; t < 2; ++t) {
        int n = t * 512 + tid;
        int r = n >> 3;
        int kc = ((n & 7) ^ (r + (r >> 3))) & 7;
        gld_lds16(qkv + ((size_t)b * 1024 + (kt + 1) * 128 + r) * 3072 + 1024 +
                      h * 64 + kc * 8,
                  sK[buf ^ 1] + n * 8);
        int d = n >> 4, s = n & 15;
        int c = s ^ (d & 7);
        gld_lds16(vbase + (size_t)d * 1024 + (kt + 1) * 128 + c * 8,
                  sV[buf ^ 1] + n * 8);
      }
    }
    const bf16_t* sKb = sK[buf];
    const bf16_t* sVb = sV[buf];

#pragma unroll
    for (int ch = 0; ch < 4; ++ch) {  // 32-k chunks
      // K A-frags: A[m=k=ch*32+kk*16+l][dk] -- i-invariant, hoisted
      bf16x8 ak[2][2];
#pragma unroll
      for (int kk = 0; kk < 2; ++kk)
#pragma unroll
        for (int ks = 0; ks < 2; ++ks)
          ak[kk][ks] = *(const bf16x8*)&sKb[sw64(ch * 32 + kk * 16 + l,
                                                 ks * 4 + quad)];
      // Vts A-frags from LDS: row d=jd*16+l, logical chunk ch*4+quad,
      // storage chunk = logical ^ (l&7)  (d&7 == l&7 since jd*16%8==0)
      bf16x8 va[4];
#pragma unroll
      for (int jd = 0; jd < 4; ++jd)
        va[jd] = *(const bf16x8*)&sVb[(jd * 16 + l) * 128 +
                                      (((ch * 4 + quad) ^ (l & 7)) << 3)];
#pragma unroll
      for (int i = 0; i < 2; ++i) {  // q-tiles
        __builtin_amdgcn_s_setprio(1);
        // Ss^T tiles (kk=0,1); Q pre-scaled by C2
        f32x4 st0 = {0.f, 0.f, 0.f, 0.f}, st1 = {0.f, 0.f, 0.f, 0.f};
        st0 = mfma16(ak[0][0], bq[i][0], st0);
        st0 = mfma16(ak[0][1], bq[i][1], st0);
        st1 = mfma16(ak[1][0], bq[i][0], st1);
        st1 = mfma16(ak[1][1], bq[i][1], st1);
        // pc = exp2(Ss^T) concatenated: slot quad*8+j <-> Vts storage slot
        bf16x8 pc;
#pragma unroll
        for (int t = 0; t < 4; ++t) {
          pc[t] = (bf16_t)exp2c(st0[t]);
          pc[4 + t] = (bf16_t)exp2c(st1[t]);
        }
#pragma unroll
        for (int jd = 0; jd < 4; ++jd)
          o[i][jd] = mfma16(va[jd], pc, o[i][jd]);
        __builtin_amdgcn_s_setprio(0);
      }
    }
  }
  // epilogue: q = qt*256+wave*32+i*16+l, d = jd*16+quad*4+{0..3} -> 8B stores
#pragma unroll
  for (int i = 0; i < 2; ++i) {
    size_t row = (size_t)b * 1024 + qt * 256 + wave * 32 + i * 16 + l;
#pragma unroll
    for (int jd = 0; jd < 4; ++jd) {
      bf16x4 pk;
#pragma unroll
      for (int t = 0; t < 4; ++t) pk[t] = (bf16_t)sanit(o[i][jd][t]);
      *(bf16x4*)&attn[row * 3072 + h * 64 + jd * 16 + quad * 4] = pk;
    }
  }
}

extern "C" void kernel_launch(void* const* d_in, const int* in_sizes, int n_in,
                              void* d_out, int out_size, void* d_ws, size_t ws_size,
                              hipStream_t stream) {
  (void)in_sizes; (void)n_in; (void)out_size; (void)ws_size;
  char* w = (char*)d_ws;
  bf16_t* qkv = (bf16_t*)w;                 // [0, 50331648)
  bf16_t* xb = (bf16_t*)(w + 50331648);     // [50331648, 67108864) -> Vts after K1
  bf16_t* Vts = xb;
  bf16_t* Wqkvb = (bf16_t*)(w + 67108864);  // [67108864, 73400320)
  bf16_t* Wprojb = (bf16_t*)(w + 73400320); // [73400320, 75497472)
  int* flag = (int*)(w + 75497472);
  bf16_t* attn = qkv + 2048;                // V-columns of qkv, stride 3072

  // convert: self-probing dtype (writes flag for K4); Q-rows scaled by C2
  convert_in<<<6144, 256, 0, stream>>>(d_in[0], d_in[1], d_in[2],
                                       xb, Wqkvb, Wprojb, flag);

  // K1: qkv = x @ Wqkv^T  (8192 x 3072, K=1024), grid 24*64=1536 (%8==0)
  gemm_bt<<<dim3(24, 64), 256, 0, stream>>>(xb, 1024, Wqkvb, qkv, nullptr, 3072,
                                            1024, nullptr);
  // K2: column-softmax denominators folded into Vts (permuted layout)
  attn_stats<<<dim3(128, 8), 256, 0, stream>>>(qkv, Vts);
  // K3: attention output -> qkv V-columns (512 thr, 256 q-rows/block)
  attn_out_k<<<dim3(128, 4), 512, 0, stream>>>(qkv, Vts, attn);
  // K4: out = attn @ Wproj^T  (8192 x 1024, K=1024), grid 8*64=512 (%8==0)
  gemm_bt<<<dim3(8, 64), 256, 0, stream>>>(attn, 3072, Wprojb, (bf16_t*)d_out,
                                           (float*)d_out, 1024, 1024, flag);
}